// Round 2
// baseline (178.664 us; speedup 1.0000x reference)
//
#include <hip/hip_runtime.h>

// SWT-Haar level-1 MSE loss == plain MSE(x, target).
// Identity: with d = x-t, dr = roll(d,-1):
//   (cA_x-cA_t)^2 + (cD_x-cD_t)^2 = 0.5[(d+dr)^2 + (dr-d)^2] = d^2 + dr^2,
//   sum(dr^2) == sum(d^2) (circular shift is a permutation per row),
//   so mean over the 2N stacked coeffs = sum(d^2)/N = MSE(x, t).
// Memory-bound streaming reduction over 2 x 50.3 MB of f32.
//
// Single fused kernel: per-block partials + device-scope counter; the last
// block to arrive reduces the 2048 partials and writes the scalar output.
// Counter is zeroed by a 4-byte memset node each call (ws is poisoned 0xAA
// once before timing). Deterministic: fixed partial slots, fixed sum order.

typedef float v4f __attribute__((ext_vector_type(4)));

#define NBLOCKS 2048   // 8 blocks/CU x 256 CUs -> fully co-resident
#define NTHREADS 256

__global__ __launch_bounds__(NTHREADS)
void swt_mse_fused(const v4f* __restrict__ x, const v4f* __restrict__ t,
                   double* __restrict__ part, unsigned int* __restrict__ count,
                   float* __restrict__ out, int n4, double invN) {
    const int tid = blockIdx.x * NTHREADS + threadIdx.x;
    const int stride = NBLOCKS * NTHREADS;

    float acc = 0.0f;  // <=24 f32 terms/thread: accumulation error negligible
    if (n4 == 6 * stride) {
        // Exact-fit fast path: 12 independent nontemporal dwordx4 loads.
        #pragma unroll
        for (int k = 0; k < 6; ++k) {
            v4f a = __builtin_nontemporal_load(x + tid + k * stride);
            v4f b = __builtin_nontemporal_load(t + tid + k * stride);
            v4f d = a - b;
            acc += d.x * d.x + d.y * d.y + d.z * d.z + d.w * d.w;
        }
    } else {
        for (int i = tid; i < n4; i += stride) {
            v4f a = x[i], b = t[i];
            v4f d = a - b;
            acc += d.x * d.x + d.y * d.y + d.z * d.z + d.w * d.w;
        }
    }

    // wave64 butterfly reduce (double)
    double dacc = (double)acc;
    #pragma unroll
    for (int off = 32; off > 0; off >>= 1)
        dacc += __shfl_down(dacc, off, 64);

    __shared__ double sm[NTHREADS / 64];
    __shared__ int lastflag;
    const int lane = threadIdx.x & 63;
    const int wid  = threadIdx.x >> 6;
    if (lane == 0) sm[wid] = dacc;
    __syncthreads();
    if (threadIdx.x == 0) {
        double s = sm[0] + sm[1] + sm[2] + sm[3];
        // release the partial, then signal arrival (device scope: 8 XCDs,
        // per-XCD L2s are not cross-coherent -> agent-scope atomics required)
        __hip_atomic_store(&part[blockIdx.x], s,
                           __ATOMIC_RELEASE, __HIP_MEMORY_SCOPE_AGENT);
        unsigned int old = __hip_atomic_fetch_add(
            count, 1u, __ATOMIC_ACQ_REL, __HIP_MEMORY_SCOPE_AGENT);
        lastflag = (old == NBLOCKS - 1);
    }
    __syncthreads();  // lastflag is block-uniform after this

    if (lastflag) {
        double a2 = 0.0;
        for (int i = threadIdx.x; i < NBLOCKS; i += NTHREADS)
            a2 += __hip_atomic_load(&part[i],
                                    __ATOMIC_RELAXED, __HIP_MEMORY_SCOPE_AGENT);
        #pragma unroll
        for (int off = 32; off > 0; off >>= 1)
            a2 += __shfl_down(a2, off, 64);
        __shared__ double sm2[NTHREADS / 64];
        if (lane == 0) sm2[wid] = a2;
        __syncthreads();
        if (threadIdx.x == 0)
            out[0] = (float)((sm2[0] + sm2[1] + sm2[2] + sm2[3]) * invN);
    }
}

extern "C" void kernel_launch(void* const* d_in, const int* in_sizes, int n_in,
                              void* d_out, int out_size, void* d_ws, size_t ws_size,
                              hipStream_t stream) {
    const float* x = (const float*)d_in[0];
    const float* t = (const float*)d_in[1];
    float* out = (float*)d_out;
    double* part = (double*)d_ws;                       // 2048 * 8 B
    unsigned int* count =
        (unsigned int*)((char*)d_ws + NBLOCKS * sizeof(double));

    long long N = (long long)in_sizes[0];   // 16*3*512*512 = 12,582,912
    int n4 = (int)(N / 4);                  // divisible by 4

    hipMemsetAsync(count, 0, sizeof(unsigned int), stream);  // graph-safe node
    swt_mse_fused<<<NBLOCKS, NTHREADS, 0, stream>>>(
        (const v4f*)x, (const v4f*)t, part, count, out, n4, 1.0 / (double)N);
}

// Round 3
// 131.501 us; speedup vs baseline: 1.3587x; 1.3587x over previous
//
#include <hip/hip_runtime.h>

// SWT-Haar level-1 MSE loss == plain MSE(x, target).
// Identity: with d = x-t, dr = roll(d,-1):
//   (cA_x-cA_t)^2 + (cD_x-cD_t)^2 = 0.5[(d+dr)^2 + (dr-d)^2] = d^2 + dr^2,
//   sum(dr^2) == sum(d^2) (circular shift is a permutation per row),
//   so mean over the 2N stacked coeffs = sum(d^2)/N = MSE(x, t).
// Memory-bound streaming reduction over 2 x 50.3 MB of f32.
//
// R2 post-mortem: __builtin_nontemporal_load collapsed BW to 283 GB/s
// (cache-bypass path). Reverted to plain dwordx4 loads; fusion kept.

typedef float v4f __attribute__((ext_vector_type(4)));

#define NBLOCKS 2048   // 8 blocks/CU x 256 CUs -> fully co-resident
#define NTHREADS 256

__global__ __launch_bounds__(NTHREADS)
void swt_mse_fused(const v4f* __restrict__ x, const v4f* __restrict__ t,
                   double* __restrict__ part, unsigned int* __restrict__ count,
                   float* __restrict__ out, int n4, double invN) {
    const int tid = blockIdx.x * NTHREADS + threadIdx.x;
    const int stride = NBLOCKS * NTHREADS;

    float acc = 0.0f;  // <=24 f32 terms/thread: accumulation error negligible
    if (n4 == 6 * stride) {
        // Exact-fit fast path: 12 independent dwordx4 loads in flight.
        #pragma unroll
        for (int k = 0; k < 6; ++k) {
            v4f a = x[tid + k * stride];
            v4f b = t[tid + k * stride];
            v4f d = a - b;
            acc += d.x * d.x + d.y * d.y + d.z * d.z + d.w * d.w;
        }
    } else {
        for (int i = tid; i < n4; i += stride) {
            v4f a = x[i], b = t[i];
            v4f d = a - b;
            acc += d.x * d.x + d.y * d.y + d.z * d.z + d.w * d.w;
        }
    }

    // wave64 butterfly reduce (double)
    double dacc = (double)acc;
    #pragma unroll
    for (int off = 32; off > 0; off >>= 1)
        dacc += __shfl_down(dacc, off, 64);

    __shared__ double sm[NTHREADS / 64];
    __shared__ int lastflag;
    const int lane = threadIdx.x & 63;
    const int wid  = threadIdx.x >> 6;
    if (lane == 0) sm[wid] = dacc;
    __syncthreads();
    if (threadIdx.x == 0) {
        double s = sm[0] + sm[1] + sm[2] + sm[3];
        // release the partial, then signal arrival (device scope: 8 XCDs,
        // per-XCD L2s are not cross-coherent -> agent-scope atomics required)
        __hip_atomic_store(&part[blockIdx.x], s,
                           __ATOMIC_RELEASE, __HIP_MEMORY_SCOPE_AGENT);
        unsigned int old = __hip_atomic_fetch_add(
            count, 1u, __ATOMIC_ACQ_REL, __HIP_MEMORY_SCOPE_AGENT);
        lastflag = (old == NBLOCKS - 1);
    }
    __syncthreads();  // lastflag is block-uniform after this

    if (lastflag) {
        double a2 = 0.0;
        for (int i = threadIdx.x; i < NBLOCKS; i += NTHREADS)
            a2 += __hip_atomic_load(&part[i],
                                    __ATOMIC_RELAXED, __HIP_MEMORY_SCOPE_AGENT);
        #pragma unroll
        for (int off = 32; off > 0; off >>= 1)
            a2 += __shfl_down(a2, off, 64);
        __shared__ double sm2[NTHREADS / 64];
        if (lane == 0) sm2[wid] = a2;
        __syncthreads();
        if (threadIdx.x == 0)
            out[0] = (float)((sm2[0] + sm2[1] + sm2[2] + sm2[3]) * invN);
    }
}

extern "C" void kernel_launch(void* const* d_in, const int* in_sizes, int n_in,
                              void* d_out, int out_size, void* d_ws, size_t ws_size,
                              hipStream_t stream) {
    const float* x = (const float*)d_in[0];
    const float* t = (const float*)d_in[1];
    float* out = (float*)d_out;
    double* part = (double*)d_ws;                       // 2048 * 8 B
    unsigned int* count =
        (unsigned int*)((char*)d_ws + NBLOCKS * sizeof(double));

    long long N = (long long)in_sizes[0];   // 16*3*512*512 = 12,582,912
    int n4 = (int)(N / 4);                  // divisible by 4

    hipMemsetAsync(count, 0, sizeof(unsigned int), stream);  // graph-safe node
    swt_mse_fused<<<NBLOCKS, NTHREADS, 0, stream>>>(
        (const v4f*)x, (const v4f*)t, part, count, out, n4, 1.0 / (double)N);
}

// Round 4
// 46.783 us; speedup vs baseline: 3.8190x; 2.8109x over previous
//
#include <hip/hip_runtime.h>

// SWT-Haar level-1 MSE loss == plain MSE(x, target).
// Identity: with d = x-t, dr = roll(d,-1):
//   (cA_x-cA_t)^2 + (cD_x-cD_t)^2 = 0.5[(d+dr)^2 + (dr-d)^2] = d^2 + dr^2,
//   sum(dr^2) == sum(d^2) (circular shift is a permutation per row),
//   so mean over the 2N stacked coeffs = sum(d^2)/N = MSE(x, t).
//
// R3 post-mortem: agent-scope RELEASE/ACQ_REL atomics were the 7x regression
// (per-block buffer_wbl2/buffer_inv L2 maintenance across 8 XCDs), NOT the
// nt-loads. Fix: single relaxed u64 atomicAdd packing {fixed-point partial
// << 12 | arrival count}. The RMW return value is hardware-serialized, so
// the last-arriving block reads the exact total from `old + packed` -- no
// partials array, no release/acquire, no cache flushes. Integer addition
// commutes => bit-deterministic output. Load loop identical to round 1.

typedef float v4f __attribute__((ext_vector_type(4)));

#define NBLOCKS 2048   // 8 blocks/CU x 256 CUs
#define NTHREADS 256
#define FPS 4194304.0  // 2^22 fixed-point scale; sum ~2.5e7 -> ~4.3e17 packed,
                       // 21x headroom below 2^63; quantization ~1e-11 relative

__global__ __launch_bounds__(NTHREADS)
void swt_mse_fused(const v4f* __restrict__ x, const v4f* __restrict__ t,
                   unsigned long long* __restrict__ acc64,
                   float* __restrict__ out, int n4, double invN) {
    const int tid = blockIdx.x * NTHREADS + threadIdx.x;
    const int stride = NBLOCKS * NTHREADS;

    float acc = 0.0f;  // <=24 f32 terms/thread: accumulation error negligible
    for (int i = tid; i < n4; i += stride) {
        v4f a = x[i], b = t[i];
        v4f d = a - b;
        acc += d.x * d.x + d.y * d.y + d.z * d.z + d.w * d.w;
    }

    // wave64 butterfly reduce (double)
    double dacc = (double)acc;
    #pragma unroll
    for (int off = 32; off > 0; off >>= 1)
        dacc += __shfl_down(dacc, off, 64);

    __shared__ double sm[NTHREADS / 64];
    const int lane = threadIdx.x & 63;
    const int wid  = threadIdx.x >> 6;
    if (lane == 0) sm[wid] = dacc;
    __syncthreads();

    if (threadIdx.x == 0) {
        double s = sm[0] + sm[1] + sm[2] + sm[3];  // s >= 0
        // pack: fixed-point value in bits [12,63], arrival count in [0,11]
        unsigned long long packed =
            ((unsigned long long)(long long)(s * FPS + 0.5) << 12) | 1ull;
        // relaxed device-scope RMW: coherence-point ALU, no wbl2/buffer_inv
        unsigned long long old = atomicAdd(acc64, packed);
        if ((old & 0xFFFull) == (unsigned long long)(NBLOCKS - 1)) {
            // last arrival: old + packed is the exact grid total
            unsigned long long total = (old + packed) >> 12;
            out[0] = (float)(((double)total / FPS) * invN);
        }
    }
}

extern "C" void kernel_launch(void* const* d_in, const int* in_sizes, int n_in,
                              void* d_out, int out_size, void* d_ws, size_t ws_size,
                              hipStream_t stream) {
    const float* x = (const float*)d_in[0];
    const float* t = (const float*)d_in[1];
    float* out = (float*)d_out;
    unsigned long long* acc64 = (unsigned long long*)d_ws;

    long long N = (long long)in_sizes[0];   // 16*3*512*512 = 12,582,912
    int n4 = (int)(N / 4);                  // divisible by 4

    hipMemsetAsync(acc64, 0, sizeof(unsigned long long), stream);  // graph-safe
    swt_mse_fused<<<NBLOCKS, NTHREADS, 0, stream>>>(
        (const v4f*)x, (const v4f*)t, acc64, out, n4, 1.0 / (double)N);
}

// Round 5
// 26.204 us; speedup vs baseline: 6.8181x; 1.7853x over previous
//
#include <hip/hip_runtime.h>

// SWT-Haar level-1 MSE loss == plain MSE(x, target).
// Identity: with d = x-t, dr = roll(d,-1):
//   (cA_x-cA_t)^2 + (cD_x-cD_t)^2 = 0.5[(d+dr)^2 + (dr-d)^2] = d^2 + dr^2,
//   sum(dr^2) == sum(d^2) (circular shift is a permutation per row),
//   so mean over the 2N stacked coeffs = sum(d^2)/N = MSE(x, t).
//
// R4 post-mortem: replays run with inputs fully L3-resident (hbm_bytes 65 KB)
// yet still took 40 us -> not BW-bound; the 2048 same-address atomicAdd
// round-trips serialize at ~20 ns each. Fix: 256 blocks x 1024 threads
// (8x fewer atomics), deep-unrolled loads (12 float4-pairs/thread in chunks
// of 4) to saturate L3/HBM from 16 waves/CU. Packed fixed-point u64 atomic
// kept (relaxed, no fences): count in bits[0,11], value*2^22 in bits[12,63].
// Integer addition commutes => bit-deterministic across arrival orders.

typedef float v4f __attribute__((ext_vector_type(4)));

#define NBLOCKS 256    // 1 block/CU
#define NTHREADS 1024  // 16 waves/CU
#define PAIRS 12       // n4 / (NBLOCKS*NTHREADS) for N = 16*3*512*512
#define FPS 4194304.0  // 2^22 fixed-point scale; total ~2.5e7*2^22 ~= 2^47,
                       // well under the 52-bit value field

__global__ __launch_bounds__(NTHREADS)
void swt_mse_fused(const v4f* __restrict__ x, const v4f* __restrict__ t,
                   unsigned long long* __restrict__ acc64,
                   float* __restrict__ out, int n4, double invN) {
    const int tid = blockIdx.x * NTHREADS + threadIdx.x;
    const int stride = NBLOCKS * NTHREADS;

    float acc = 0.0f;  // <=48 f32 terms/thread: accumulation error negligible
    if (n4 == PAIRS * stride) {
        // Exact-fit fast path: chunks of 4 pairs -> 8 dwordx4 loads batched
        // per chunk (~64 VGPR live), 3 chunks.
        #pragma unroll
        for (int c = 0; c < PAIRS / 4; ++c) {
            v4f a0 = x[tid + (4 * c + 0) * stride];
            v4f a1 = x[tid + (4 * c + 1) * stride];
            v4f a2 = x[tid + (4 * c + 2) * stride];
            v4f a3 = x[tid + (4 * c + 3) * stride];
            v4f b0 = t[tid + (4 * c + 0) * stride];
            v4f b1 = t[tid + (4 * c + 1) * stride];
            v4f b2 = t[tid + (4 * c + 2) * stride];
            v4f b3 = t[tid + (4 * c + 3) * stride];
            v4f d0 = a0 - b0, d1 = a1 - b1, d2 = a2 - b2, d3 = a3 - b3;
            acc += d0.x * d0.x + d0.y * d0.y + d0.z * d0.z + d0.w * d0.w;
            acc += d1.x * d1.x + d1.y * d1.y + d1.z * d1.z + d1.w * d1.w;
            acc += d2.x * d2.x + d2.y * d2.y + d2.z * d2.z + d2.w * d2.w;
            acc += d3.x * d3.x + d3.y * d3.y + d3.z * d3.z + d3.w * d3.w;
        }
    } else {
        for (int i = tid; i < n4; i += stride) {
            v4f a = x[i], b = t[i];
            v4f d = a - b;
            acc += d.x * d.x + d.y * d.y + d.z * d.z + d.w * d.w;
        }
    }

    // wave64 butterfly reduce (double)
    double dacc = (double)acc;
    #pragma unroll
    for (int off = 32; off > 0; off >>= 1)
        dacc += __shfl_down(dacc, off, 64);

    __shared__ double sm[NTHREADS / 64];
    const int lane = threadIdx.x & 63;
    const int wid  = threadIdx.x >> 6;
    if (lane == 0) sm[wid] = dacc;
    __syncthreads();

    if (threadIdx.x == 0) {
        double s = 0.0;
        #pragma unroll
        for (int w = 0; w < NTHREADS / 64; ++w) s += sm[w];  // s >= 0
        // pack: fixed-point value in bits [12,63], arrival count in [0,11]
        unsigned long long packed =
            ((unsigned long long)(long long)(s * FPS + 0.5) << 12) | 1ull;
        // relaxed device-scope RMW: no wbl2/buffer_inv cache maintenance
        unsigned long long old = atomicAdd(acc64, packed);
        if ((old & 0xFFFull) == (unsigned long long)(NBLOCKS - 1)) {
            // last arrival: old + packed is the exact grid total
            unsigned long long total = (old + packed) >> 12;
            out[0] = (float)(((double)total / FPS) * invN);
        }
    }
}

extern "C" void kernel_launch(void* const* d_in, const int* in_sizes, int n_in,
                              void* d_out, int out_size, void* d_ws, size_t ws_size,
                              hipStream_t stream) {
    const float* x = (const float*)d_in[0];
    const float* t = (const float*)d_in[1];
    float* out = (float*)d_out;
    unsigned long long* acc64 = (unsigned long long*)d_ws;

    long long N = (long long)in_sizes[0];   // 16*3*512*512 = 12,582,912
    int n4 = (int)(N / 4);                  // divisible by 4

    hipMemsetAsync(acc64, 0, sizeof(unsigned long long), stream);  // graph-safe
    swt_mse_fused<<<NBLOCKS, NTHREADS, 0, stream>>>(
        (const v4f*)x, (const v4f*)t, acc64, out, n4, 1.0 / (double)N);
}